// Round 7
// baseline (933.994 us; speedup 1.0000x reference)
//
#include <hip/hip_runtime.h>
#include <hip/hip_bf16.h>

typedef __hip_bfloat16 bf16;
typedef short s16x8 __attribute__((ext_vector_type(8)));
typedef float f32x4 __attribute__((ext_vector_type(4)));

// ---------------- workspace layout (bytes) ----------------
// cf_t  (float, [2][14][14][256])      @ 0          401,408
// Wp    (bf16,  [9][256][512])         @ 401,408    2,359,296
// scale (float,[256]) @ 2,760,704 ; shift @ 2,761,728
// Xq    (bf16, [512 n][16 k][258 rows][32ci] pre-swizzled, 64B/row pitch)
//       @ 2,762,752  size 512*16*16,512 = 135,266,304
#define OFF_WP    401408
#define OFF_SCALE 2760704
#define OFF_SHIFT 2761728
#define OFF_XQ    2762752
#define XQ_SLICE  16512   // 258 rows * 64 B

// swizzle: byte ^= ((row>>1)&3)<<4 (within-64B-row involution, bits 4-5 only)

// ---------------- kernel 1: bilinear resize features -> cf_t[b][y][x][c] ----------------
__global__ void k_resize(const float* __restrict__ feat, float* __restrict__ cf_t) {
    int idx = blockIdx.x * 256 + threadIdx.x;      // 2*14*14*256 = 100352
    if (idx >= 2 * 14 * 14 * 256) return;
    int c  = idx & 255;
    int sp = idx >> 8;
    int x  = sp % 14;
    int y  = (sp / 14) % 14;
    int b  = sp / 196;
    const float sy = 96.0f / 14.0f, sx = 128.0f / 14.0f;
    float s = fmaxf(((float)y + 0.5f) * sy - 0.5f, 0.0f);
    int y0 = min((int)floorf(s), 95); int y1 = min(y0 + 1, 95); float wy = s - (float)y0;
    float t = fmaxf(((float)x + 0.5f) * sx - 0.5f, 0.0f);
    int x0 = min((int)floorf(t), 127); int x1 = min(x0 + 1, 127); float wx = t - (float)x0;
    const float* f = feat + (size_t)(b * 256 + c) * 96 * 128;
    float v00 = f[y0 * 128 + x0], v01 = f[y0 * 128 + x1];
    float v10 = f[y1 * 128 + x0], v11 = f[y1 * 128 + x1];
    float r0 = v00 * (1.f - wy) + v10 * wy;
    float r1 = v01 * (1.f - wy) + v11 * wy;
    cf_t[idx] = r0 * (1.f - wx) + r1 * wx;
}

// ---------------- kernel 2: pack weights + fold BN (Wp[tap][co][ci]) ----------------
__global__ void k_packw(const float* __restrict__ w, const float* __restrict__ cb,
                        const float* __restrict__ g, const float* __restrict__ be,
                        const float* __restrict__ mean, const float* __restrict__ var,
                        bf16* __restrict__ Wp, float* __restrict__ scale, float* __restrict__ shift) {
    int idx = blockIdx.x * 256 + threadIdx.x;      // 9*256*512
    if (idx < 256) {
        float inv = rsqrtf(var[idx] + 1e-5f);
        float sc = g[idx] * inv;
        scale[idx] = sc;
        shift[idx] = (cb[idx] - mean[idx]) * sc + be[idx];
    }
    if (idx >= 9 * 256 * 512) return;
    int ci  = idx & 511;
    int co  = (idx >> 9) & 255;
    int tap = idx >> 17;
    Wp[idx] = __float2bfloat16(w[(co * 512 + ci) * 9 + tap]);
}

// ---------------- kernel 3: build pre-swizzled per-(n,k) B slices ----------------
__global__ __launch_bounds__(256) void k_build(const float* __restrict__ mask,
                                               const float* __restrict__ boxes,
                                               const float* __restrict__ cf_t,
                                               char* __restrict__ Xq) {
    int n = blockIdx.x, c = threadIdx.x;
    char* Xn = Xq + (size_t)n * (16 * XQ_SLICE);

    // zero ONLY rows the payload loop never writes (borders + 2-row tail):
    // row r unwritten iff r>=256 || (r>>4)∈{0,15} || (r&15)∈{0,15}  (62 rows)
    // thread c zeroes dword (c&15) of row r in k-slice (c>>4).
    for (int r = 0; r < 258; ++r) {
        int ry = r >> 4, rx = r & 15;
        if (r >= 256 || ry == 0 || ry == 15 || rx == 0 || rx == 15) {
            *((unsigned int*)(Xn + (c >> 4) * XQ_SLICE + r * 64) + (c & 15)) = 0u;
        }
    }

    __shared__ int   YL0[14], YL1[14], XL0[14], XL1[14];
    __shared__ float WY[14], WX[14];

    int b = n >> 8, i = n & 255;
    const float* pb = boxes + (b * 256 + i) * 4;
    int xa = (int)(pb[0] * 0.125f), ya = (int)(pb[1] * 0.125f);
    int xb = (int)(pb[2] * 0.125f), yb = (int)(pb[3] * 0.125f);
    if (xb - xa < 1) { if (xb == 14) xa -= 1; else xb += 1; }
    if (yb - ya < 1) { if (yb == 14) ya -= 1; else yb += 1; }

    if (c < 14) {
        float nf = (float)(yb - ya);
        float s = fmaxf(((float)c + 0.5f) * nf / 14.0f - 0.5f, 0.0f);
        int i0 = min((int)floorf(s), yb - ya - 1);
        int i1 = min(i0 + 1, yb - ya - 1);
        YL0[c] = ya + i0; YL1[c] = ya + i1; WY[c] = s - (float)i0;
    } else if (c < 28) {
        int ox = c - 14;
        float nf = (float)(xb - xa);
        float s = fmaxf(((float)ox + 0.5f) * nf / 14.0f - 0.5f, 0.0f);
        int i0 = min((int)floorf(s), xb - xa - 1);
        int i1 = min(i0 + 1, xb - xa - 1);
        XL0[ox] = xa + i0; XL1[ox] = xa + i1; WX[ox] = s - (float)i0;
    }
    __syncthreads();

    const float* mrow = mask + (size_t)(n * 256 + c) * 196;
    const float* cfb  = cf_t + (size_t)b * 196 * 256;
    int e2 = (c & 31) * 2;
    char* p0 = Xn + (c >> 5) * XQ_SLICE;          // mask channels: ci = c      -> k = c>>5
    char* p1 = p0 + 8 * XQ_SLICE;                 // crop channels: ci = c+256  -> k = 8+(c>>5)
    for (int s = 0; s < 196; ++s) {
        int oy = s / 14, ox = s % 14;
        int prow = (oy + 1) * 16 + (ox + 1);
        int swz = (prow * 64 + e2) ^ (((prow >> 1) & 3) << 4);
        *(bf16*)(p0 + swz) = __float2bfloat16(mrow[s]);
        int Y0 = YL0[oy], Y1 = YL1[oy], X0 = XL0[ox], X1 = XL1[ox];
        float wy = WY[oy], wx = WX[ox];
        float v00 = cfb[(Y0 * 14 + X0) * 256 + c];
        float v01 = cfb[(Y0 * 14 + X1) * 256 + c];
        float v10 = cfb[(Y1 * 14 + X0) * 256 + c];
        float v11 = cfb[(Y1 * 14 + X1) * 256 + c];
        float r0 = v00 * (1.f - wy) + v10 * wy;
        float r1 = v01 * (1.f - wy) + v11 * wy;
        *(bf16*)(p1 + swz) = __float2bfloat16(r0 * (1.f - wx) + r1 * wx);
    }
}

// ---------------- kernel 4: implicit-GEMM conv, LDS-dbuf B, 2-deep reg-prefetch A ----------------
// grid 1024: blk -> (n = blk>>1, co-half = blk&1). block = 256 thr = 4 waves
// (2 wm x 2 wn), tile 128co x 224px. 16 k-steps (32ci each), 1 barrier/step,
// 9 taps inner read the SAME staged 258-row slice.
// A-prefetch is 2-deep (A0/A1 only): round 6's 3-deep rotation (+16 VGPR) spilled
// (WRITE_SIZE 604MB vs 105MB baseline). Peak ~90 VGPR + 112 AGPR here.
__global__ __launch_bounds__(256, 2) void k_conv(const bf16* __restrict__ Wp,
                                                 const char* __restrict__ Xq,
                                                 const float* __restrict__ scale,
                                                 const float* __restrict__ shift,
                                                 float* __restrict__ out) {
    __shared__ alignas(16) char smem[2][XQ_SLICE];
    int blk = blockIdx.x;
    int n = blk >> 1, cbh = (blk & 1) << 7;
    int tid = threadIdx.x;
    int wv = tid >> 6, l = tid & 63;
    int wm = wv >> 1, wn = wv & 1;
    int lr = l & 15, lk = l >> 4;
    int co_base = cbh + wm * 64;
    int px_base = wn * 112;
    const char* XqN = Xq + (size_t)n * (16 * XQ_SLICE);

    int aoffb[4];
#pragma unroll
    for (int m = 0; m < 4; ++m) aoffb[m] = (co_base + m * 16 + lr) * 512 + lk * 8;
    int rb64[7];
#pragma unroll
    for (int j = 0; j < 7; ++j) rb64[j] = (px_base + j * 16 + lr) << 6;
    int lkx = lk << 4;
    int xts[3];
#pragma unroll
    for (int kw = 0; kw < 3; ++kw) xts[kw] = lkx ^ ((((lr + kw) >> 1) & 3) << 4);

    f32x4 acc[4][7];
#pragma unroll
    for (int m = 0; m < 4; ++m)
#pragma unroll
        for (int j = 0; j < 7; ++j) acc[m][j] = f32x4{0.f, 0.f, 0.f, 0.f};

    s16x8 A0[4], A1[4];

#define STAGE(BUF, K) do {                                                        \
        const char* _s = XqN + (K) * XQ_SLICE;                                    \
        char* _d = &smem[BUF][0];                                                 \
        __builtin_amdgcn_global_load_lds(_s + tid * 16,         _d + tid * 16,         16, 0, 0); \
        __builtin_amdgcn_global_load_lds(_s + 4096  + tid * 16, _d + 4096  + tid * 16, 16, 0, 0); \
        __builtin_amdgcn_global_load_lds(_s + 8192  + tid * 16, _d + 8192  + tid * 16, 16, 0, 0); \
        __builtin_amdgcn_global_load_lds(_s + 12288 + tid * 16, _d + 12288 + tid * 16, 16, 0, 0); \
        if (tid < 8)                                                              \
        __builtin_amdgcn_global_load_lds(_s + 16384 + tid * 16, _d + 16384 + tid * 16, 16, 0, 0); \
    } while (0)

#define LOADA(AR, TAP, K) do {                                                    \
        const bf16* _w = Wp + (TAP) * 131072 + (K) * 32;                          \
        AR[0] = *(const s16x8*)(_w + aoffb[0]);                                   \
        AR[1] = *(const s16x8*)(_w + aoffb[1]);                                   \
        AR[2] = *(const s16x8*)(_w + aoffb[2]);                                   \
        AR[3] = *(const s16x8*)(_w + aoffb[3]);                                   \
    } while (0)

#define COMPUTE(TAP, BUF, AR) do {                                                \
        const char* _sb = &smem[BUF][0];                                          \
        int _ab = ((((TAP) / 3) * 16 + (TAP) % 3) << 6) + xts[(TAP) % 3];         \
        s16x8 bfr[7];                                                             \
        _Pragma("unroll")                                                         \
        for (int j = 0; j < 7; ++j) bfr[j] = *(const s16x8*)(_sb + rb64[j] + _ab);\
        _Pragma("unroll")                                                         \
        for (int m = 0; m < 4; ++m)                                               \
            _Pragma("unroll")                                                     \
            for (int j = 0; j < 7; ++j)                                           \
                acc[m][j] = __builtin_amdgcn_mfma_f32_16x16x32_bf16(AR[m], bfr[j], acc[m][j], 0, 0, 0); \
    } while (0)

// consume taps 0..8, tap t from (t even ? Aa : Ab); prefetch tap t+1 during tap t.
// Ends with next k-step's tap0 prefetched into Ab -> call sites alternate (A0,A1)/(A1,A0).
#define STEPK(K, BUF, Aa, Ab) do {                                                \
        if ((K) < 15) STAGE((BUF) ^ 1, (K) + 1);                                  \
        LOADA(Ab, 1, (K));  COMPUTE(0, BUF, Aa);                                  \
        LOADA(Aa, 2, (K));  COMPUTE(1, BUF, Ab);                                  \
        LOADA(Ab, 3, (K));  COMPUTE(2, BUF, Aa);                                  \
        LOADA(Aa, 4, (K));  COMPUTE(3, BUF, Ab);                                  \
        LOADA(Ab, 5, (K));  COMPUTE(4, BUF, Aa);                                  \
        LOADA(Aa, 6, (K));  COMPUTE(5, BUF, Ab);                                  \
        LOADA(Ab, 7, (K));  COMPUTE(6, BUF, Aa);                                  \
        LOADA(Aa, 8, (K));  COMPUTE(7, BUF, Ab);                                  \
        if ((K) < 15) { LOADA(Ab, 0, (K) + 1); }                                  \
        COMPUTE(8, BUF, Aa);                                                      \
        __syncthreads();                                                          \
    } while (0)

    // prologue
    STAGE(0, 0);
    LOADA(A0, 0, 0);
    __syncthreads();   // implicit vmcnt(0) drain makes buf0 + A0 ready

#pragma unroll 1
    for (int kk = 0; kk < 16; kk += 2) {
        STEPK(kk,     0, A0, A1);
        STEPK(kk + 1, 1, A1, A0);
    }

    // epilogue: y = relu(acc*scale + shift); D layout: col=lane&15, row=(lane>>4)*4+r
#pragma unroll
    for (int m = 0; m < 4; ++m) {
        f32x4 sc = *(const f32x4*)(scale + co_base + m * 16 + lk * 4);
        f32x4 sh = *(const f32x4*)(shift + co_base + m * 16 + lk * 4);
#pragma unroll
        for (int j = 0; j < 7; ++j) {
            int px = px_base + j * 16 + lr;
            int pxx = px & 15, py = px >> 4;
            if (pxx < 14) {
                float* op = out + (size_t)(n * 256 + co_base + m * 16 + lk * 4) * 196 + py * 14 + pxx;
#pragma unroll
                for (int r = 0; r < 4; ++r) {
                    float y = acc[m][j][r] * sc[r] + sh[r];
                    op[r * 196] = fmaxf(y, 0.f);
                }
            }
        }
    }
#undef STAGE
#undef LOADA
#undef COMPUTE
#undef STEPK
}

extern "C" void kernel_launch(void* const* d_in, const int* in_sizes, int n_in,
                              void* d_out, int out_size, void* d_ws, size_t ws_size,
                              hipStream_t stream) {
    const float* features = (const float*)d_in[0];
    const float* boxes    = (const float*)d_in[1];
    const float* mask     = (const float*)d_in[2];
    const float* conv_w   = (const float*)d_in[3];
    const float* conv_b   = (const float*)d_in[4];
    const float* bn_g     = (const float*)d_in[5];
    const float* bn_b     = (const float*)d_in[6];
    const float* bn_m     = (const float*)d_in[7];
    const float* bn_v     = (const float*)d_in[8];

    char* base   = (char*)d_ws;
    float* cf_t  = (float*)(base);
    bf16*  Wp    = (bf16*)(base + OFF_WP);
    float* scale = (float*)(base + OFF_SCALE);
    float* shift = (float*)(base + OFF_SHIFT);
    char*  Xq    = (char*)(base + OFF_XQ);
    float* out   = (float*)d_out;

    k_resize<<<392, 256, 0, stream>>>(features, cf_t);
    k_packw<<<4608, 256, 0, stream>>>(conv_w, conv_b, bn_g, bn_b, bn_m, bn_v, Wp, scale, shift);
    k_build<<<512, 256, 0, stream>>>(mask, boxes, cf_t, Xq);
    k_conv<<<1024, 256, 0, stream>>>(Wp, Xq, scale, shift, out);
}